// Round 1
// baseline (92.392 us; speedup 1.0000x reference)
//
#include <hip/hip_runtime.h>

typedef __attribute__((ext_vector_type(8))) short short8;
typedef __attribute__((ext_vector_type(4))) float f32x4;

// Manual fp32 -> bf16 bits, round-to-nearest-even (finite values only).
__device__ __forceinline__ unsigned short bf16_bits(float f) {
  unsigned int u = __float_as_uint(f);
  unsigned int r = (u + 0x7FFFu + ((u >> 16) & 1u)) >> 16;
  return (unsigned short)r;
}

// ---------------------------------------------------------------------------
// Precompute: hx[512][256] = x @ W1[:128]          (fp32)
//             hy[512][256] = y @ W1[128:] + b1     (fp32)
//             W2T[n][k]    = bf16(W2[k][n])        (bf16 bits as ushort)
// grid: 384 blocks x 256 threads.
//   blocks 0..63   : hx rows 8b .. 8b+7
//   blocks 64..127 : hy rows 8(b-64) .. +7
//   blocks 128..383: W2T row n = b-128
// ---------------------------------------------------------------------------
__global__ void k_pre(const float* __restrict__ x, const float* __restrict__ y,
                      const float* __restrict__ W1, const float* __restrict__ b1,
                      const float* __restrict__ W2,
                      float* __restrict__ hx, float* __restrict__ hy,
                      unsigned short* __restrict__ W2T) {
  const int b = blockIdx.x;
  const int t = threadIdx.x;
  if (b < 128) {
    const bool isx = (b < 64);
    const int i0 = (isx ? b : (b - 64)) * 8;
    const float* __restrict__ src = isx ? x : y;
    const float* __restrict__ W = W1 + (isx ? 0 : 128 * 256);
    float acc[8];
    const float binit = isx ? 0.0f : b1[t];
#pragma unroll
    for (int r = 0; r < 8; ++r) acc[r] = binit;
    for (int d = 0; d < 128; ++d) {
      const float wv = W[d * 256 + t];  // coalesced across t
#pragma unroll
      for (int r = 0; r < 8; ++r) acc[r] += src[(i0 + r) * 128 + d] * wv;  // uniform (scalar) loads
    }
    float* __restrict__ dst = isx ? hx : hy;
#pragma unroll
    for (int r = 0; r < 8; ++r) dst[(i0 + r) * 256 + t] = acc[r];
  } else {
    const int n = b - 128;
    W2T[n * 256 + t] = bf16_bits(W2[t * 256 + n]);
  }
}

// ---------------------------------------------------------------------------
// Main fused kernel. Block = 256 threads (4 waves).
// Tile: 1 i x 64 j pairs (BM=64 rows), full N=256 (each wave owns 64 cols),
// K=256 in 8 steps of BK=32.
// A_lds[64][264] bf16 : A[r][k] = relu(hx[i][k] + hy[j0+r][k]) (row pad +8)
// Bt  [256][40]  bf16 : W2T slice [n][k_local], row pad +8 (stride 20 dwords)
// MFMA v_mfma_f32_16x16x32_bf16, frag layout:
//   A: row = lane&15, k = 8*(lane>>4)+e ; B: col = lane&15, k = 8*(lane>>4)+e
//   C: col = lane&15, row = 4*(lane>>4)+reg   (guide-verified)
// Epilogue: u = relu(C + b2); score = sum_n u*W3[n] + b3 -> out[i*512+j0+r]
// ---------------------------------------------------------------------------
__launch_bounds__(256)
__global__ void k_main(const float* __restrict__ hx, const float* __restrict__ hy,
                       const unsigned short* __restrict__ W2T,
                       const float* __restrict__ b2, const float* __restrict__ W3,
                       const float* __restrict__ b3, float* __restrict__ out) {
  __shared__ unsigned short A_lds[64 * 264];  // 33792 B
  __shared__ unsigned short Bt[256 * 40];     // 20480 B
  __shared__ float hx_s[256];                 // 1024 B
  __shared__ float red[64 * 4];               // 1024 B

  const int tid = threadIdx.x;
  const int lane = tid & 63;
  const int w = tid >> 6;       // wave id 0..3 -> n-slice w*64
  const int l15 = lane & 15;
  const int l4 = lane >> 4;
  const int i = blockIdx.x >> 3;
  const int j0 = (blockIdx.x & 7) * 64;

  hx_s[tid] = hx[i * 256 + tid];
  __syncthreads();

  // ---- A generation: 64 rows x 256 k, coalesced over hy ----
  {
    const int kcol = (tid & 63) * 4;
#pragma unroll
    for (int it = 0; it < 16; ++it) {
      const int row = it * 4 + w;
      const float4 hv = *reinterpret_cast<const float4*>(&hy[(j0 + row) * 256 + kcol]);
      const float4 xv = *reinterpret_cast<const float4*>(&hx_s[kcol]);
      const float a0 = fmaxf(hv.x + xv.x, 0.0f);
      const float a1 = fmaxf(hv.y + xv.y, 0.0f);
      const float a2 = fmaxf(hv.z + xv.z, 0.0f);
      const float a3 = fmaxf(hv.w + xv.w, 0.0f);
      uint2 pk;
      pk.x = (unsigned int)bf16_bits(a0) | ((unsigned int)bf16_bits(a1) << 16);
      pk.y = (unsigned int)bf16_bits(a2) | ((unsigned int)bf16_bits(a3) << 16);
      *reinterpret_cast<uint2*>(&A_lds[row * 264 + kcol]) = pk;
    }
  }
  // (first __syncthreads inside K-loop covers A_lds writes)

  f32x4 acc[4][4];
#pragma unroll
  for (int mf = 0; mf < 4; ++mf)
#pragma unroll
    for (int nf = 0; nf < 4; ++nf) acc[mf][nf] = (f32x4){0.f, 0.f, 0.f, 0.f};

  for (int kk = 0; kk < 8; ++kk) {
    // ---- stage Bt: W2T[0..255][kk*32 .. +31], coalesced 16B chunks ----
#pragma unroll
    for (int it = 0; it < 4; ++it) {
      const int c = it * 256 + tid;  // 1024 chunks of 16B
      const int n = c >> 2;
      const int pos = c & 3;
      const uint4 v = *reinterpret_cast<const uint4*>(&W2T[n * 256 + kk * 32 + pos * 8]);
      *reinterpret_cast<uint4*>(&Bt[n * 40 + pos * 8]) = v;
    }
    __syncthreads();

    short8 af[4], bfr[4];
#pragma unroll
    for (int mf = 0; mf < 4; ++mf)
      af[mf] = *reinterpret_cast<const short8*>(&A_lds[(mf * 16 + l15) * 264 + kk * 32 + l4 * 8]);
#pragma unroll
    for (int nf = 0; nf < 4; ++nf) {
      const int n = w * 64 + nf * 16 + l15;
      bfr[nf] = *reinterpret_cast<const short8*>(&Bt[n * 40 + l4 * 8]);
    }
#pragma unroll
    for (int mf = 0; mf < 4; ++mf)
#pragma unroll
      for (int nf = 0; nf < 4; ++nf)
        acc[mf][nf] = __builtin_amdgcn_mfma_f32_16x16x32_bf16(af[mf], bfr[nf], acc[mf][nf], 0, 0, 0);
    __syncthreads();
  }

  // ---- fused epilogue: relu(C+b2) . W3, reduce over n ----
  float w3v[4], b2v[4];
#pragma unroll
  for (int nf = 0; nf < 4; ++nf) {
    const int c = w * 64 + nf * 16 + l15;
    b2v[nf] = b2[c];
    w3v[nf] = W3[c];
  }
#pragma unroll
  for (int mf = 0; mf < 4; ++mf) {
#pragma unroll
    for (int reg = 0; reg < 4; ++reg) {
      float p = 0.0f;
#pragma unroll
      for (int nf = 0; nf < 4; ++nf)
        p += fmaxf(acc[mf][nf][reg] + b2v[nf], 0.0f) * w3v[nf];
      // reduce across the 16 lanes sharing this output row (cols)
#pragma unroll
      for (int m = 1; m < 16; m <<= 1) p += __shfl_xor(p, m, 64);
      if (l15 == 0) red[(mf * 16 + l4 * 4 + reg) * 4 + w] = p;
    }
  }
  __syncthreads();
  if (tid < 64) {
    const float s = red[tid * 4 + 0] + red[tid * 4 + 1] + red[tid * 4 + 2] + red[tid * 4 + 3] + b3[0];
    out[i * 512 + j0 + tid] = s;
  }
}

extern "C" void kernel_launch(void* const* d_in, const int* in_sizes, int n_in,
                              void* d_out, int out_size, void* d_ws, size_t ws_size,
                              hipStream_t stream) {
  const float* x  = (const float*)d_in[0];
  const float* y  = (const float*)d_in[1];
  const float* W1 = (const float*)d_in[2];
  const float* b1 = (const float*)d_in[3];
  const float* W2 = (const float*)d_in[4];
  const float* b2 = (const float*)d_in[5];
  const float* W3 = (const float*)d_in[6];
  const float* b3 = (const float*)d_in[7];
  float* out = (float*)d_out;

  char* ws = (char*)d_ws;
  float* hx = (float*)ws;                                   // 512*256*4 = 524288 B
  float* hy = (float*)(ws + 524288);                        // 524288 B
  unsigned short* W2T = (unsigned short*)(ws + 1048576);    // 131072 B

  k_pre<<<384, 256, 0, stream>>>(x, y, W1, b1, W2, hx, hy, W2T);
  k_main<<<4096, 256, 0, stream>>>(hx, hy, W2T, b2, W3, b3, out);
}